// Round 3
// baseline (2520.938 us; speedup 1.0000x reference)
//
#include <hip/hip_runtime.h>
#include <stdint.h>

static constexpr int NU    = 100000;
static constexpr int NI    = 200000;
static constexpr int D     = 64;
static constexpr int E_UI  = 3200000;
static constexpr int E_SOC = 1600000;
#define EPS_LN 1e-5f

// ----------------- CSR build -----------------
__global__ void hist_kernel(const int* __restrict__ ui_src, const int* __restrict__ ui_dst,
                            const int* __restrict__ soc_src,
                            int* __restrict__ c_us, int* __restrict__ c_ud, int* __restrict__ c_ss)
{
    int e = blockIdx.x * blockDim.x + threadIdx.x;
    if (e < E_UI) {
        atomicAdd(&c_us[ui_src[e]], 1);
        atomicAdd(&c_ud[ui_dst[e]], 1);
    }
    if (e < E_SOC) atomicAdd(&c_ss[soc_src[e]], 1);
}

__global__ void scan_partial(const int* __restrict__ cnt, int* __restrict__ bsum, int n)
{
    __shared__ int lds[256];
    int i = blockIdx.x * 256 + threadIdx.x;
    lds[threadIdx.x] = (i < n) ? cnt[i] : 0;
    __syncthreads();
    for (int off = 128; off > 0; off >>= 1) {
        if (threadIdx.x < off) lds[threadIdx.x] += lds[threadIdx.x + off];
        __syncthreads();
    }
    if (threadIdx.x == 0) bsum[blockIdx.x] = lds[0];
}

__global__ void scan_bsums(int* __restrict__ bsum, int nb)
{
    __shared__ int lds[1024];
    int t = threadIdx.x;
    int v = (t < nb) ? bsum[t] : 0;
    lds[t] = v;
    __syncthreads();
    for (int off = 1; off < 1024; off <<= 1) {
        int add = (t >= off) ? lds[t - off] : 0;
        __syncthreads();
        lds[t] += add;
        __syncthreads();
    }
    if (t < nb) bsum[t] = lds[t] - v;   // exclusive scan of block sums
}

__global__ void scan_final(const int* __restrict__ cnt, const int* __restrict__ bsum,
                           int* __restrict__ rowptr, int* __restrict__ cursor, int n, int total)
{
    __shared__ int lds[256];
    int i = blockIdx.x * 256 + threadIdx.x;
    int v = (i < n) ? cnt[i] : 0;
    lds[threadIdx.x] = v;
    __syncthreads();
    for (int off = 1; off < 256; off <<= 1) {
        int add = (threadIdx.x >= off) ? lds[threadIdx.x - off] : 0;
        __syncthreads();
        lds[threadIdx.x] += add;
        __syncthreads();
    }
    if (i < n) {
        int excl = bsum[blockIdx.x] + lds[threadIdx.x] - v;
        rowptr[i] = excl;
        cursor[i] = excl;
    }
    if (i == 0) rowptr[n] = total;
}

__global__ void scatter_kernel(const int* __restrict__ ui_src, const int* __restrict__ ui_dst,
                               const float* __restrict__ ui_val,
                               const int* __restrict__ soc_src, const int* __restrict__ soc_dst,
                               const float* __restrict__ soc_val,
                               int* __restrict__ cur_us, int* __restrict__ cur_ud, int* __restrict__ cur_ss,
                               int2* __restrict__ rec_us, int2* __restrict__ rec_ud, int2* __restrict__ rec_ss)
{
    int e = blockIdx.x * blockDim.x + threadIdx.x;
    if (e < E_UI) {
        int s = ui_src[e], d = ui_dst[e];
        int v = __float_as_int(ui_val[e]);
        int p = atomicAdd(&cur_us[s], 1);
        rec_us[p] = make_int2(d, v);
        int q = atomicAdd(&cur_ud[d], 1);
        rec_ud[q] = make_int2(s, v);
    }
    if (e < E_SOC) {
        int s = soc_src[e], d = soc_dst[e];
        int v = __float_as_int(soc_val[e]);
        int p = atomicAdd(&cur_ss[s], 1);
        rec_ss[p] = make_int2(d, v);
    }
}

__global__ void copy0_kernel(const float4* __restrict__ src, float4* __restrict__ a,
                             float4* __restrict__ b, int n4)
{
    int i = blockIdx.x * blockDim.x + threadIdx.x;
    if (i < n4) { float4 v = src[i]; a[i] = v; b[i] = v; }
}

// fused SPMM + GEMV(@W + bias) + residual + LayerNorm; one 64-lane wave per row
__global__ void __launch_bounds__(256) fused_layer(
    const float* __restrict__ xin, const float* __restrict__ gsrc,
    float* __restrict__ yout,
    const int* __restrict__ rowptr, const int2* __restrict__ recs,
    const float* __restrict__ W, const float* __restrict__ bias,
    const float* __restrict__ gamma, const float* __restrict__ beta,
    int nrows)
{
    __shared__ float Wl[64 * 64];
    {
        const float4* W4 = (const float4*)W;
        float4* Wl4 = (float4*)Wl;
        for (int i = threadIdx.x; i < 1024; i += 256) Wl4[i] = W4[i];
    }
    __syncthreads();
    int wid  = (blockIdx.x * 256 + threadIdx.x) >> 6;
    int lane = threadIdx.x & 63;
    if (wid >= nrows) return;

    // SpMM row: acc[lane] = sum_e val_e * gsrc[idx_e][lane]
    float acc = 0.f;
    int beg = rowptr[wid], end = rowptr[wid + 1];
    for (int j = beg; j < end; ++j) {
        int2 rec = recs[j];
        acc += __int_as_float(rec.y) * gsrc[rec.x * 64 + lane];
    }
    // GEMV: z[lane] = bias[lane] + sum_k acc[k] * W[k][lane]
    float z = bias[lane];
    #pragma unroll
    for (int k = 0; k < 64; ++k)
        z += __shfl(acc, k) * Wl[k * 64 + lane];
    // residual + LayerNorm across the 64 lanes
    float t = xin[wid * 64 + lane] + z;
    float s = t;
    #pragma unroll
    for (int off = 32; off > 0; off >>= 1) s += __shfl_xor(s, off);
    float mean = s * (1.0f / 64.0f);
    float dv = t - mean;
    float q = dv * dv;
    #pragma unroll
    for (int off = 32; off > 0; off >>= 1) q += __shfl_xor(q, off);
    float var = q * (1.0f / 64.0f);
    float y = dv * rsqrtf(var + EPS_LN) * gamma[lane] + beta[lane];
    yout[wid * 64 + lane] = y;
}

extern "C" void kernel_launch(void* const* d_in, const int* in_sizes, int n_in,
                              void* d_out, int out_size, void* d_ws, size_t ws_size,
                              hipStream_t stream)
{
    const float* user_emb = (const float*)d_in[0];
    const float* item_emb = (const float*)d_in[1];
    const int*   ui_src   = (const int*)d_in[2];
    const int*   ui_dst   = (const int*)d_in[3];
    const float* ui_val   = (const float*)d_in[4];
    const int*   soc_src  = (const int*)d_in[5];
    const int*   soc_dst  = (const int*)d_in[6];
    const float* soc_val  = (const float*)d_in[7];
    const float* W_ui     = (const float*)d_in[8];
    const float* b_ui     = (const float*)d_in[9];
    const float* W_soc    = (const float*)d_in[10];
    const float* b_soc    = (const float*)d_in[11];
    const float* ln_g     = (const float*)d_in[12];
    const float* ln_b     = (const float*)d_in[13];

    float* out     = (float*)d_out;
    float* out_ui  = out;                         // [3][NU][D]
    float* out_soc = out + (size_t)3 * NU * D;    // [3][NU][D]
    float* out_it  = out + (size_t)6 * NU * D;    // [NI][D]

    // ---- workspace carve (all 256B-aligned) ----
    char* p = (char*)d_ws;
    auto take = [&](size_t bytes) { char* r = p; p += (bytes + 255) & ~(size_t)255; return r; };
    int* c_us   = (int*)take((size_t)NU * 4);
    int* c_ud   = (int*)take((size_t)NI * 4);
    int* c_ss   = (int*)take((size_t)NU * 4);
    int* cur_us = (int*)take((size_t)NU * 4);
    int* cur_ud = (int*)take((size_t)NI * 4);
    int* cur_ss = (int*)take((size_t)NU * 4);
    int* rp_us  = (int*)take((size_t)(NU + 1) * 4);
    int* rp_ud  = (int*)take((size_t)(NI + 1) * 4);
    int* rp_ss  = (int*)take((size_t)(NU + 1) * 4);
    int* bsum   = (int*)take(1024 * 4);
    int2* rec_us = (int2*)take((size_t)E_UI * 8);
    int2* rec_ud = (int2*)take((size_t)E_UI * 8);
    int2* rec_ss = (int2*)take((size_t)E_SOC * 8);

    // ---- CSR build ----
    // c_us, c_ud, c_ss are contiguous in the carve (pads included) — one memset.
    hipMemsetAsync(c_us, 0, (char*)cur_us - (char*)c_us, stream);

    int ethreads = 256;
    int eblocks  = (E_UI + ethreads - 1) / ethreads;
    hist_kernel<<<eblocks, ethreads, 0, stream>>>(ui_src, ui_dst, soc_src, c_us, c_ud, c_ss);

    auto run_scan = [&](const int* cnt, int* rowptr, int* cursor, int n, int total) {
        int nb = (n + 255) / 256;
        scan_partial<<<nb, 256, 0, stream>>>(cnt, bsum, n);
        scan_bsums<<<1, 1024, 0, stream>>>(bsum, nb);
        scan_final<<<nb, 256, 0, stream>>>(cnt, bsum, rowptr, cursor, n, total);
    };
    run_scan(c_us, rp_us, cur_us, NU, E_UI);
    run_scan(c_ud, rp_ud, cur_ud, NI, E_UI);
    run_scan(c_ss, rp_ss, cur_ss, NU, E_SOC);

    scatter_kernel<<<eblocks, ethreads, 0, stream>>>(ui_src, ui_dst, ui_val,
                                                     soc_src, soc_dst, soc_val,
                                                     cur_us, cur_ud, cur_ss,
                                                     rec_us, rec_ud, rec_ss);

    // ---- layer 0 outputs: ui_list[0] = soc_list[0] = user_emb ----
    int n4 = NU * D / 4;
    copy0_kernel<<<(n4 + 255) / 256, 256, 0, stream>>>((const float4*)user_emb,
                                                       (float4*)out_ui, (float4*)out_soc, n4);

    const float* u0 = user_emb;
    float* u1 = out_ui + (size_t)NU * D;
    float* u2 = out_ui + (size_t)2 * NU * D;
    const float* s0 = user_emb;
    float* s1 = out_soc + (size_t)NU * D;
    float* s2 = out_soc + (size_t)2 * NU * D;

    int ublocks = (NU + 3) / 4;   // 4 waves per 256-thread block
    int iblocks = (NI + 3) / 4;

    // ---- layer 0 ----
    // users:   u1 = LN(u0 + spmm(ui_by_src, it0) @ W_ui[0] + b_ui[0]; ln[0])
    fused_layer<<<ublocks, 256, 0, stream>>>(u0, item_emb, u1, rp_us, rec_us,
                                             W_ui + 0 * 4096, b_ui + 0 * 64,
                                             ln_g + 0 * 64, ln_b + 0 * 64, NU);
    // items:   it1 = LN(it0 + spmm(ui_by_dst, u0) @ W_ui[0] + b_ui[0]; ln[1])
    fused_layer<<<iblocks, 256, 0, stream>>>(item_emb, u0, out_it, rp_ud, rec_ud,
                                             W_ui + 0 * 4096, b_ui + 0 * 64,
                                             ln_g + 1 * 64, ln_b + 1 * 64, NI);
    // social:  s1 = LN(s0 + spmm(soc_by_src, s0) @ W_soc[0] + b_soc[0]; ln[0])
    fused_layer<<<ublocks, 256, 0, stream>>>(s0, s0, s1, rp_ss, rec_ss,
                                             W_soc + 0 * 4096, b_soc + 0 * 64,
                                             ln_g + 0 * 64, ln_b + 0 * 64, NU);

    // ---- layer 1 ----
    // users:   u2 = LN(u1 + spmm(ui_by_src, it1) @ W_ui[1] + b_ui[1]; ln[2])
    fused_layer<<<ublocks, 256, 0, stream>>>(u1, out_it, u2, rp_us, rec_us,
                                             W_ui + 1 * 4096, b_ui + 1 * 64,
                                             ln_g + 2 * 64, ln_b + 2 * 64, NU);
    // items:   it2 = LN(it1 + spmm(ui_by_dst, u1) @ W_ui[1] + b_ui[1]; ln[3])  (in place)
    fused_layer<<<iblocks, 256, 0, stream>>>(out_it, u1, out_it, rp_ud, rec_ud,
                                             W_ui + 1 * 4096, b_ui + 1 * 64,
                                             ln_g + 3 * 64, ln_b + 3 * 64, NI);
    // social:  s2 = LN(s1 + spmm(soc_by_src, s1) @ W_soc[1] + b_soc[1]; ln[2])
    fused_layer<<<ublocks, 256, 0, stream>>>(s1, s1, s2, rp_ss, rec_ss,
                                             W_soc + 1 * 4096, b_soc + 1 * 64,
                                             ln_g + 2 * 64, ln_b + 2 * 64, NU);
}

// Round 5
// 2073.241 us; speedup vs baseline: 1.2159x; 1.2159x over previous
//
#include <hip/hip_runtime.h>
#include <stdint.h>

static constexpr int NU    = 100000;
static constexpr int NI    = 200000;
static constexpr int D     = 64;
static constexpr int E_UI  = 3200000;
static constexpr int E_SOC = 1600000;
static constexpr int CH    = 8192;   // edges per binning block
static constexpr int BROWS = 512;    // rows per bucket
#define EPS_LN 1e-5f

// ---------- phase 1: per-block bucket histogram ----------
__global__ void __launch_bounds__(256) bin_count(
    const int* __restrict__ rows, int E, int nblk, int nb, int* __restrict__ cnt)
{
    __shared__ int hist[512];
    int b = blockIdx.x, t = threadIdx.x;
    for (int i = t; i < nb; i += 256) hist[i] = 0;
    __syncthreads();
    int e0 = b * CH, e1 = min(E, e0 + CH);
    for (int e = e0 + t; e < e1; e += 256)
        atomicAdd(&hist[rows[e] >> 9], 1);
    __syncthreads();
    for (int i = t; i < nb; i += 256) cnt[i * nblk + b] = hist[i];  // bucket-major
}

// ---------- generic 3-level exclusive scan ----------
__global__ void scan_partial(const int* __restrict__ cnt, int* __restrict__ bsum, int n)
{
    __shared__ int lds[256];
    int i = blockIdx.x * 256 + threadIdx.x;
    lds[threadIdx.x] = (i < n) ? cnt[i] : 0;
    __syncthreads();
    for (int off = 128; off > 0; off >>= 1) {
        if (threadIdx.x < off) lds[threadIdx.x] += lds[threadIdx.x + off];
        __syncthreads();
    }
    if (threadIdx.x == 0) bsum[blockIdx.x] = lds[0];
}

__global__ void scan_bsums(int* __restrict__ bsum, int nb)
{
    __shared__ int lds[1024];
    int t = threadIdx.x;
    int v = (t < nb) ? bsum[t] : 0;
    lds[t] = v;
    __syncthreads();
    for (int off = 1; off < 1024; off <<= 1) {
        int add = (t >= off) ? lds[t - off] : 0;
        __syncthreads();
        lds[t] += add;
        __syncthreads();
    }
    if (t < nb) bsum[t] = lds[t] - v;   // exclusive scan of block sums
}

__global__ void scan_out(const int* __restrict__ cnt, const int* __restrict__ bsum,
                         int* __restrict__ ofs, int n)
{
    __shared__ int lds[256];
    int i = blockIdx.x * 256 + threadIdx.x;
    int v = (i < n) ? cnt[i] : 0;
    lds[threadIdx.x] = v;
    __syncthreads();
    for (int off = 1; off < 256; off <<= 1) {
        int add = (threadIdx.x >= off) ? lds[threadIdx.x - off] : 0;
        __syncthreads();
        lds[threadIdx.x] += add;
        __syncthreads();
    }
    if (i < n) ofs[i] = bsum[blockIdx.x] + lds[threadIdx.x] - v;
}

// ---------- phase 2: bucket-binned scatter (LDS cursors, no global atomics) ----------
__global__ void __launch_bounds__(256) bin_scatter(
    const int* __restrict__ rows, const int* __restrict__ idxs, const float* __restrict__ vals,
    int E, int nblk, const int* __restrict__ ofs, int nb, int2* __restrict__ binned)
{
    __shared__ int cur[512];
    int b = blockIdx.x, t = threadIdx.x;
    for (int i = t; i < nb; i += 256) cur[i] = ofs[i * nblk + b];
    __syncthreads();
    int e0 = b * CH, e1 = min(E, e0 + CH);
    for (int e = e0 + t; e < e1; e += 256) {
        int row = rows[e];
        int bucket = row >> 9;
        int slot = atomicAdd(&cur[bucket], 1);
        unsigned pack = ((unsigned)(row & 511) << 23) | (unsigned)idxs[e];
        binned[slot] = make_int2((int)pack, __float_as_int(vals[e]));
    }
}

// ---------- phase 3: per-bucket fine scatter into row-sorted CSR ----------
__global__ void __launch_bounds__(512) fine_scatter(
    const int2* __restrict__ binned, const int* __restrict__ ofs, int nblk, int nb,
    int E, int nrows, int* __restrict__ rowptr, int2* __restrict__ rec)
{
    __shared__ int hist[512];
    __shared__ int cur[512];
    int b = blockIdx.x, t = threadIdx.x;
    int beg = ofs[b * nblk];
    int end = (b + 1 < nb) ? ofs[(b + 1) * nblk] : E;

    hist[t] = 0;
    __syncthreads();
    for (int j = beg + t; j < end; j += 512)
        atomicAdd(&hist[((unsigned)binned[j].x) >> 23], 1);
    __syncthreads();
    int v = hist[t];
    // inclusive Hillis-Steele scan over 512
    for (int off = 1; off < 512; off <<= 1) {
        int add = (t >= off) ? hist[t - off] : 0;
        __syncthreads();
        hist[t] += add;
        __syncthreads();
    }
    int excl = hist[t] - v;
    cur[t] = excl;
    int grow = b * BROWS + t;
    if (grow <= nrows) rowptr[grow] = beg + excl;   // covers rowptr[nrows]=E in last bucket
    __syncthreads();
    for (int j = beg + t; j < end; j += 512) {
        int2 eb = binned[j];
        unsigned p = (unsigned)eb.x;
        int rl  = (int)(p >> 23);
        int idx = (int)(p & 0x7FFFFFu);
        int c = atomicAdd(&cur[rl], 1);
        rec[beg + c] = make_int2(idx, eb.y);
    }
}

__global__ void copy0_kernel(const float4* __restrict__ src, float4* __restrict__ a,
                             float4* __restrict__ b, int n4)
{
    int i = blockIdx.x * blockDim.x + threadIdx.x;
    if (i < n4) { float4 v = src[i]; a[i] = v; b[i] = v; }
}

// fused SPMM + GEMV(@W + bias) + residual + LayerNorm; one 64-lane wave per row
__global__ void __launch_bounds__(256) fused_layer(
    const float* __restrict__ xin, const float* __restrict__ gsrc,
    float* __restrict__ yout,
    const int* __restrict__ rowptr, const int2* __restrict__ recs,
    const float* __restrict__ W, const float* __restrict__ bias,
    const float* __restrict__ gamma, const float* __restrict__ beta,
    int nrows)
{
    __shared__ float Wl[64 * 64];
    {
        const float4* W4 = (const float4*)W;
        float4* Wl4 = (float4*)Wl;
        for (int i = threadIdx.x; i < 1024; i += 256) Wl4[i] = W4[i];
    }
    __syncthreads();
    int wid  = (blockIdx.x * 256 + threadIdx.x) >> 6;
    int lane = threadIdx.x & 63;
    if (wid >= nrows) return;

    float acc = 0.f;
    int beg = rowptr[wid], end = rowptr[wid + 1];
    for (int j = beg; j < end; ++j) {
        int2 rec = recs[j];
        acc += __int_as_float(rec.y) * gsrc[rec.x * 64 + lane];
    }
    float z = bias[lane];
    #pragma unroll
    for (int k = 0; k < 64; ++k)
        z += __shfl(acc, k) * Wl[k * 64 + lane];
    float t = xin[wid * 64 + lane] + z;
    float s = t;
    #pragma unroll
    for (int off = 32; off > 0; off >>= 1) s += __shfl_xor(s, off);
    float mean = s * (1.0f / 64.0f);
    float dv = t - mean;
    float q = dv * dv;
    #pragma unroll
    for (int off = 32; off > 0; off >>= 1) q += __shfl_xor(q, off);
    float var = q * (1.0f / 64.0f);
    float y = dv * rsqrtf(var + EPS_LN) * gamma[lane] + beta[lane];
    yout[wid * 64 + lane] = y;
}

extern "C" void kernel_launch(void* const* d_in, const int* in_sizes, int n_in,
                              void* d_out, int out_size, void* d_ws, size_t ws_size,
                              hipStream_t stream)
{
    const float* user_emb = (const float*)d_in[0];
    const float* item_emb = (const float*)d_in[1];
    const int*   ui_src   = (const int*)d_in[2];
    const int*   ui_dst   = (const int*)d_in[3];
    const float* ui_val   = (const float*)d_in[4];
    const int*   soc_src  = (const int*)d_in[5];
    const int*   soc_dst  = (const int*)d_in[6];
    const float* soc_val  = (const float*)d_in[7];
    const float* W_ui     = (const float*)d_in[8];
    const float* b_ui     = (const float*)d_in[9];
    const float* W_soc    = (const float*)d_in[10];
    const float* b_soc    = (const float*)d_in[11];
    const float* ln_g     = (const float*)d_in[12];
    const float* ln_b     = (const float*)d_in[13];

    float* out     = (float*)d_out;
    float* out_ui  = out;                         // [3][NU][D]
    float* out_soc = out + (size_t)3 * NU * D;    // [3][NU][D]
    float* out_it  = out + (size_t)6 * NU * D;    // [NI][D]

    // bucket/block geometry
    const int NBU = (NU + BROWS - 1) / BROWS;     // 196 user buckets
    const int NBI = (NI + BROWS - 1) / BROWS;     // 391 item buckets
    const int BLK_UI  = (E_UI  + CH - 1) / CH;    // 391
    const int BLK_SOC = (E_SOC + CH - 1) / CH;    // 196

    // ---- workspace carve (256B-aligned) ----
    char* p = (char*)d_ws;
    auto take = [&](size_t bytes) { char* r = p; p += (bytes + 255) & ~(size_t)255; return r; };
    int2* rec_us = (int2*)take((size_t)E_UI * 8);
    int2* rec_ud = (int2*)take((size_t)E_UI * 8);
    int2* rec_ss = (int2*)take((size_t)E_SOC * 8);
    int2* binned = (int2*)take((size_t)E_UI * 8);      // reused by all three tasks
    int*  rp_us  = (int*)take((size_t)(NU + 1) * 4);
    int*  rp_ud  = (int*)take((size_t)(NI + 1) * 4);
    int*  rp_ss  = (int*)take((size_t)(NU + 1) * 4);
    int*  cnt    = (int*)take((size_t)NBI * BLK_UI * 4);   // max 152881
    int*  ofs    = (int*)take((size_t)NBI * BLK_UI * 4);
    int*  bsum   = (int*)take(1024 * 4);

    auto build_csr = [&](const int* rows, const int* idxs, const float* vals,
                         int E, int nblk, int nb, int nrows, int* rowptr, int2* rec) {
        bin_count<<<nblk, 256, 0, stream>>>(rows, E, nblk, nb, cnt);
        int n = nb * nblk;
        int sb = (n + 255) / 256;
        scan_partial<<<sb, 256, 0, stream>>>(cnt, bsum, n);
        scan_bsums<<<1, 1024, 0, stream>>>(bsum, sb);
        scan_out<<<sb, 256, 0, stream>>>(cnt, bsum, ofs, n);
        bin_scatter<<<nblk, 256, 0, stream>>>(rows, idxs, vals, E, nblk, ofs, nb, binned);
        fine_scatter<<<nb, 512, 0, stream>>>(binned, ofs, nblk, nb, E, nrows, rowptr, rec);
    };

    build_csr(ui_src,  ui_dst,  ui_val,  E_UI,  BLK_UI,  NBU, NU, rp_us, rec_us);
    build_csr(ui_dst,  ui_src,  ui_val,  E_UI,  BLK_UI,  NBI, NI, rp_ud, rec_ud);
    build_csr(soc_src, soc_dst, soc_val, E_SOC, BLK_SOC, NBU, NU, rp_ss, rec_ss);

    // ---- layer 0 outputs: ui_list[0] = soc_list[0] = user_emb ----
    int n4 = NU * D / 4;
    copy0_kernel<<<(n4 + 255) / 256, 256, 0, stream>>>((const float4*)user_emb,
                                                       (float4*)out_ui, (float4*)out_soc, n4);

    const float* u0 = user_emb;
    float* u1 = out_ui + (size_t)NU * D;
    float* u2 = out_ui + (size_t)2 * NU * D;
    const float* s0 = user_emb;
    float* s1 = out_soc + (size_t)NU * D;
    float* s2 = out_soc + (size_t)2 * NU * D;

    int ublocks = (NU + 3) / 4;   // 4 waves per 256-thread block
    int iblocks = (NI + 3) / 4;

    // ---- layer 0 ----
    fused_layer<<<ublocks, 256, 0, stream>>>(u0, item_emb, u1, rp_us, rec_us,
                                             W_ui + 0 * 4096, b_ui + 0 * 64,
                                             ln_g + 0 * 64, ln_b + 0 * 64, NU);
    fused_layer<<<iblocks, 256, 0, stream>>>(item_emb, u0, out_it, rp_ud, rec_ud,
                                             W_ui + 0 * 4096, b_ui + 0 * 64,
                                             ln_g + 1 * 64, ln_b + 1 * 64, NI);
    fused_layer<<<ublocks, 256, 0, stream>>>(s0, s0, s1, rp_ss, rec_ss,
                                             W_soc + 0 * 4096, b_soc + 0 * 64,
                                             ln_g + 0 * 64, ln_b + 0 * 64, NU);

    // ---- layer 1 ----
    fused_layer<<<ublocks, 256, 0, stream>>>(u1, out_it, u2, rp_us, rec_us,
                                             W_ui + 1 * 4096, b_ui + 1 * 64,
                                             ln_g + 2 * 64, ln_b + 2 * 64, NU);
    fused_layer<<<iblocks, 256, 0, stream>>>(out_it, u1, out_it, rp_ud, rec_ud,
                                             W_ui + 1 * 4096, b_ui + 1 * 64,
                                             ln_g + 3 * 64, ln_b + 3 * 64, NI);
    fused_layer<<<ublocks, 256, 0, stream>>>(s1, s1, s2, rp_ss, rec_ss,
                                             W_soc + 1 * 4096, b_soc + 1 * 64,
                                             ln_g + 2 * 64, ln_b + 2 * 64, NU);
}

// Round 6
// 1421.913 us; speedup vs baseline: 1.7729x; 1.4581x over previous
//
#include <hip/hip_runtime.h>
#include <stdint.h>

static constexpr int NU    = 100000;
static constexpr int NI    = 200000;
static constexpr int D     = 64;
static constexpr int E_UI  = 3200000;
static constexpr int E_SOC = 1600000;
static constexpr int CH    = 8192;   // edges per binning block
static constexpr int BROWS = 512;    // rows per bucket
#define EPS_LN 1e-5f

// ---------- phase 1: per-block bucket histogram ----------
__global__ void __launch_bounds__(256) bin_count(
    const int* __restrict__ rows, int E, int nblk, int nb, int* __restrict__ cnt)
{
    __shared__ int hist[512];
    int b = blockIdx.x, t = threadIdx.x;
    for (int i = t; i < nb; i += 256) hist[i] = 0;
    __syncthreads();
    int e0 = b * CH, e1 = min(E, e0 + CH);
    for (int e = e0 + t; e < e1; e += 256)
        atomicAdd(&hist[rows[e] >> 9], 1);
    __syncthreads();
    for (int i = t; i < nb; i += 256) cnt[i * nblk + b] = hist[i];  // bucket-major
}

// ---------- generic 3-level exclusive scan ----------
__global__ void scan_partial(const int* __restrict__ cnt, int* __restrict__ bsum, int n)
{
    __shared__ int lds[256];
    int i = blockIdx.x * 256 + threadIdx.x;
    lds[threadIdx.x] = (i < n) ? cnt[i] : 0;
    __syncthreads();
    for (int off = 128; off > 0; off >>= 1) {
        if (threadIdx.x < off) lds[threadIdx.x] += lds[threadIdx.x + off];
        __syncthreads();
    }
    if (threadIdx.x == 0) bsum[blockIdx.x] = lds[0];
}

__global__ void scan_bsums(int* __restrict__ bsum, int nb)
{
    __shared__ int lds[1024];
    int t = threadIdx.x;
    int v = (t < nb) ? bsum[t] : 0;
    lds[t] = v;
    __syncthreads();
    for (int off = 1; off < 1024; off <<= 1) {
        int add = (t >= off) ? lds[t - off] : 0;
        __syncthreads();
        lds[t] += add;
        __syncthreads();
    }
    if (t < nb) bsum[t] = lds[t] - v;   // exclusive scan of block sums
}

__global__ void scan_out(const int* __restrict__ cnt, const int* __restrict__ bsum,
                         int* __restrict__ ofs, int n)
{
    __shared__ int lds[256];
    int i = blockIdx.x * 256 + threadIdx.x;
    int v = (i < n) ? cnt[i] : 0;
    lds[threadIdx.x] = v;
    __syncthreads();
    for (int off = 1; off < 256; off <<= 1) {
        int add = (threadIdx.x >= off) ? lds[threadIdx.x - off] : 0;
        __syncthreads();
        lds[threadIdx.x] += add;
        __syncthreads();
    }
    if (i < n) ofs[i] = bsum[blockIdx.x] + lds[threadIdx.x] - v;
}

// ---------- phase 2: bucket-binned scatter (LDS cursors, no global atomics) ----------
__global__ void __launch_bounds__(256) bin_scatter(
    const int* __restrict__ rows, const int* __restrict__ idxs, const float* __restrict__ vals,
    int E, int nblk, const int* __restrict__ ofs, int nb, int2* __restrict__ binned)
{
    __shared__ int cur[512];
    int b = blockIdx.x, t = threadIdx.x;
    for (int i = t; i < nb; i += 256) cur[i] = ofs[i * nblk + b];
    __syncthreads();
    int e0 = b * CH, e1 = min(E, e0 + CH);
    for (int e = e0 + t; e < e1; e += 256) {
        int row = rows[e];
        int bucket = row >> 9;
        int slot = atomicAdd(&cur[bucket], 1);
        unsigned pack = ((unsigned)(row & 511) << 23) | (unsigned)idxs[e];
        binned[slot] = make_int2((int)pack, __float_as_int(vals[e]));
    }
}

// ---------- phase 3: per-bucket fine scatter into row-sorted CSR ----------
__global__ void __launch_bounds__(512) fine_scatter(
    const int2* __restrict__ binned, const int* __restrict__ ofs, int nblk, int nb,
    int E, int nrows, int* __restrict__ rowptr, int2* __restrict__ rec)
{
    __shared__ int hist[512];
    __shared__ int cur[512];
    int b = blockIdx.x, t = threadIdx.x;
    int beg = ofs[b * nblk];
    int end = (b + 1 < nb) ? ofs[(b + 1) * nblk] : E;

    hist[t] = 0;
    __syncthreads();
    for (int j = beg + t; j < end; j += 512)
        atomicAdd(&hist[((unsigned)binned[j].x) >> 23], 1);
    __syncthreads();
    int v = hist[t];
    // inclusive Hillis-Steele scan over 512
    for (int off = 1; off < 512; off <<= 1) {
        int add = (t >= off) ? hist[t - off] : 0;
        __syncthreads();
        hist[t] += add;
        __syncthreads();
    }
    int excl = hist[t] - v;
    cur[t] = excl;
    int grow = b * BROWS + t;
    if (grow <= nrows) rowptr[grow] = beg + excl;   // covers rowptr[nrows]=E in last bucket
    __syncthreads();
    for (int j = beg + t; j < end; j += 512) {
        int2 eb = binned[j];
        unsigned p = (unsigned)eb.x;
        int rl  = (int)(p >> 23);
        int idx = (int)(p & 0x7FFFFFu);
        int c = atomicAdd(&cur[rl], 1);
        rec[beg + c] = make_int2(idx, eb.y);
    }
}

__global__ void copy0_kernel(const float4* __restrict__ src, float4* __restrict__ a,
                             float4* __restrict__ b, int n4)
{
    int i = blockIdx.x * blockDim.x + threadIdx.x;
    if (i < n4) { float4 v = src[i]; a[i] = v; b[i] = v; }
}

// fused SPMM + GEMV(@W + bias) + residual + LayerNorm; one 64-lane wave per row.
// SpMM gather: 16 lanes x float4 per edge row, 4 edges per wave instruction,
// 2x unrolled (8 edges in flight) for memory-level parallelism.
__global__ void __launch_bounds__(256) fused_layer(
    const float* __restrict__ xin, const float* __restrict__ gsrc,
    float* __restrict__ yout,
    const int* __restrict__ rowptr, const int2* __restrict__ recs,
    const float* __restrict__ W, const float* __restrict__ bias,
    const float* __restrict__ gamma, const float* __restrict__ beta,
    int nrows)
{
    __shared__ float Wl[64 * 64];
    {
        const float4* W4 = (const float4*)W;
        float4* Wl4 = (float4*)Wl;
        for (int i = threadIdx.x; i < 1024; i += 256) Wl4[i] = W4[i];
    }
    __syncthreads();
    int wid  = (blockIdx.x * 256 + threadIdx.x) >> 6;
    int lane = threadIdx.x & 63;
    if (wid >= nrows) return;

    int g   = lane >> 4;    // edge sub-group 0..3
    int l16 = lane & 15;    // float4 index within row

    float4 acc0 = make_float4(0.f, 0.f, 0.f, 0.f);
    float4 acc1 = make_float4(0.f, 0.f, 0.f, 0.f);
    int beg = rowptr[wid], end = rowptr[wid + 1];
    int j = beg + g;
    for (; j + 4 < end; j += 8) {
        int2 r0 = recs[j];
        int2 r1 = recs[j + 4];
        float4 v0 = ((const float4*)(gsrc + (size_t)r0.x * 64))[l16];
        float4 v1 = ((const float4*)(gsrc + (size_t)r1.x * 64))[l16];
        float w0 = __int_as_float(r0.y);
        float w1 = __int_as_float(r1.y);
        acc0.x += w0 * v0.x; acc0.y += w0 * v0.y; acc0.z += w0 * v0.z; acc0.w += w0 * v0.w;
        acc1.x += w1 * v1.x; acc1.y += w1 * v1.y; acc1.z += w1 * v1.z; acc1.w += w1 * v1.w;
    }
    if (j < end) {
        int2 r0 = recs[j];
        float4 v0 = ((const float4*)(gsrc + (size_t)r0.x * 64))[l16];
        float w0 = __int_as_float(r0.y);
        acc0.x += w0 * v0.x; acc0.y += w0 * v0.y; acc0.z += w0 * v0.z; acc0.w += w0 * v0.w;
    }
    float4 acc = make_float4(acc0.x + acc1.x, acc0.y + acc1.y,
                             acc0.z + acc1.z, acc0.w + acc1.w);
    // reduce across the 4 edge sub-groups (XOR butterfly over lanes 16, 32)
    #pragma unroll
    for (int off = 16; off <= 32; off <<= 1) {
        acc.x += __shfl_xor(acc.x, off);
        acc.y += __shfl_xor(acc.y, off);
        acc.z += __shfl_xor(acc.z, off);
        acc.w += __shfl_xor(acc.w, off);
    }
    // lane l now holds agg dims 4*(l&15)..+3 (replicated across groups)

    // GEMV: z[lane] = bias[lane] + sum_k agg[k] * W[k][lane]
    float z = bias[lane];
    #pragma unroll
    for (int q = 0; q < 16; ++q) {
        float a0 = __shfl(acc.x, q);
        float a1 = __shfl(acc.y, q);
        float a2 = __shfl(acc.z, q);
        float a3 = __shfl(acc.w, q);
        z += a0 * Wl[(4 * q + 0) * 64 + lane];
        z += a1 * Wl[(4 * q + 1) * 64 + lane];
        z += a2 * Wl[(4 * q + 2) * 64 + lane];
        z += a3 * Wl[(4 * q + 3) * 64 + lane];
    }
    // residual + LayerNorm across the 64 lanes
    float t = xin[wid * 64 + lane] + z;
    float s = t;
    #pragma unroll
    for (int off = 32; off > 0; off >>= 1) s += __shfl_xor(s, off);
    float mean = s * (1.0f / 64.0f);
    float dv = t - mean;
    float q2 = dv * dv;
    #pragma unroll
    for (int off = 32; off > 0; off >>= 1) q2 += __shfl_xor(q2, off);
    float var = q2 * (1.0f / 64.0f);
    float y = dv * rsqrtf(var + EPS_LN) * gamma[lane] + beta[lane];
    yout[wid * 64 + lane] = y;
}

extern "C" void kernel_launch(void* const* d_in, const int* in_sizes, int n_in,
                              void* d_out, int out_size, void* d_ws, size_t ws_size,
                              hipStream_t stream)
{
    const float* user_emb = (const float*)d_in[0];
    const float* item_emb = (const float*)d_in[1];
    const int*   ui_src   = (const int*)d_in[2];
    const int*   ui_dst   = (const int*)d_in[3];
    const float* ui_val   = (const float*)d_in[4];
    const int*   soc_src  = (const int*)d_in[5];
    const int*   soc_dst  = (const int*)d_in[6];
    const float* soc_val  = (const float*)d_in[7];
    const float* W_ui     = (const float*)d_in[8];
    const float* b_ui     = (const float*)d_in[9];
    const float* W_soc    = (const float*)d_in[10];
    const float* b_soc    = (const float*)d_in[11];
    const float* ln_g     = (const float*)d_in[12];
    const float* ln_b     = (const float*)d_in[13];

    float* out     = (float*)d_out;
    float* out_ui  = out;                         // [3][NU][D]
    float* out_soc = out + (size_t)3 * NU * D;    // [3][NU][D]
    float* out_it  = out + (size_t)6 * NU * D;    // [NI][D]

    // bucket/block geometry
    const int NBU = (NU + BROWS - 1) / BROWS;     // 196 user buckets
    const int NBI = (NI + BROWS - 1) / BROWS;     // 391 item buckets
    const int BLK_UI  = (E_UI  + CH - 1) / CH;    // 391
    const int BLK_SOC = (E_SOC + CH - 1) / CH;    // 196

    // ---- workspace carve (256B-aligned) ----
    char* p = (char*)d_ws;
    auto take = [&](size_t bytes) { char* r = p; p += (bytes + 255) & ~(size_t)255; return r; };
    int2* rec_us = (int2*)take((size_t)E_UI * 8);
    int2* rec_ud = (int2*)take((size_t)E_UI * 8);
    int2* rec_ss = (int2*)take((size_t)E_SOC * 8);
    int2* binned = (int2*)take((size_t)E_UI * 8);      // reused by all three tasks
    int*  rp_us  = (int*)take((size_t)(NU + 1) * 4);
    int*  rp_ud  = (int*)take((size_t)(NI + 1) * 4);
    int*  rp_ss  = (int*)take((size_t)(NU + 1) * 4);
    int*  cnt    = (int*)take((size_t)NBI * BLK_UI * 4);   // max 152881
    int*  ofs    = (int*)take((size_t)NBI * BLK_UI * 4);
    int*  bsum   = (int*)take(1024 * 4);

    auto build_csr = [&](const int* rows, const int* idxs, const float* vals,
                         int E, int nblk, int nb, int nrows, int* rowptr, int2* rec) {
        bin_count<<<nblk, 256, 0, stream>>>(rows, E, nblk, nb, cnt);
        int n = nb * nblk;
        int sb = (n + 255) / 256;
        scan_partial<<<sb, 256, 0, stream>>>(cnt, bsum, n);
        scan_bsums<<<1, 1024, 0, stream>>>(bsum, sb);
        scan_out<<<sb, 256, 0, stream>>>(cnt, bsum, ofs, n);
        bin_scatter<<<nblk, 256, 0, stream>>>(rows, idxs, vals, E, nblk, ofs, nb, binned);
        fine_scatter<<<nb, 512, 0, stream>>>(binned, ofs, nblk, nb, E, nrows, rowptr, rec);
    };

    build_csr(ui_src,  ui_dst,  ui_val,  E_UI,  BLK_UI,  NBU, NU, rp_us, rec_us);
    build_csr(ui_dst,  ui_src,  ui_val,  E_UI,  BLK_UI,  NBI, NI, rp_ud, rec_ud);
    build_csr(soc_src, soc_dst, soc_val, E_SOC, BLK_SOC, NBU, NU, rp_ss, rec_ss);

    // ---- layer 0 outputs: ui_list[0] = soc_list[0] = user_emb ----
    int n4 = NU * D / 4;
    copy0_kernel<<<(n4 + 255) / 256, 256, 0, stream>>>((const float4*)user_emb,
                                                       (float4*)out_ui, (float4*)out_soc, n4);

    const float* u0 = user_emb;
    float* u1 = out_ui + (size_t)NU * D;
    float* u2 = out_ui + (size_t)2 * NU * D;
    const float* s0 = user_emb;
    float* s1 = out_soc + (size_t)NU * D;
    float* s2 = out_soc + (size_t)2 * NU * D;

    int ublocks = (NU + 3) / 4;   // 4 waves per 256-thread block
    int iblocks = (NI + 3) / 4;

    // ---- layer 0 ----
    fused_layer<<<ublocks, 256, 0, stream>>>(u0, item_emb, u1, rp_us, rec_us,
                                             W_ui + 0 * 4096, b_ui + 0 * 64,
                                             ln_g + 0 * 64, ln_b + 0 * 64, NU);
    fused_layer<<<iblocks, 256, 0, stream>>>(item_emb, u0, out_it, rp_ud, rec_ud,
                                             W_ui + 0 * 4096, b_ui + 0 * 64,
                                             ln_g + 1 * 64, ln_b + 1 * 64, NI);
    fused_layer<<<ublocks, 256, 0, stream>>>(s0, s0, s1, rp_ss, rec_ss,
                                             W_soc + 0 * 4096, b_soc + 0 * 64,
                                             ln_g + 0 * 64, ln_b + 0 * 64, NU);

    // ---- layer 1 ----
    fused_layer<<<ublocks, 256, 0, stream>>>(u1, out_it, u2, rp_us, rec_us,
                                             W_ui + 1 * 4096, b_ui + 1 * 64,
                                             ln_g + 2 * 64, ln_b + 2 * 64, NU);
    fused_layer<<<iblocks, 256, 0, stream>>>(out_it, u1, out_it, rp_ud, rec_ud,
                                             W_ui + 1 * 4096, b_ui + 1 * 64,
                                             ln_g + 3 * 64, ln_b + 3 * 64, NI);
    fused_layer<<<ublocks, 256, 0, stream>>>(s1, s1, s2, rp_ss, rec_ss,
                                             W_soc + 1 * 4096, b_soc + 1 * 64,
                                             ln_g + 2 * 64, ln_b + 2 * 64, NU);
}